// Round 1
// baseline (560.543 us; speedup 1.0000x reference)
//
#include <hip/hip_runtime.h>
#include <hip/hip_bf16.h>
#include <stdint.h>

typedef unsigned short u16;
typedef __bf16 bf16x8 __attribute__((ext_vector_type(8)));
typedef float f32x4 __attribute__((ext_vector_type(4)));

// round-to-nearest-even f32 -> bf16 (finite inputs; -inf maps correctly)
__device__ __forceinline__ u16 f2bf(float f) {
  union { float f; uint32_t u; } v; v.f = f;
  uint32_t u = v.u;
  return (u16)((u + 0x7FFFu + ((u >> 16) & 1u)) >> 16);
}

__device__ __forceinline__ f32x4 mfma16(bf16x8 a, bf16x8 b, f32x4 c) {
  return __builtin_amdgcn_mfma_f32_16x16x32_bf16(a, b, c, 0, 0, 0);
}

// ---------------- f32 -> bf16 conversion, 4 elts/thread ----------------
__global__ void cvt_bf16(const float* __restrict__ src, u16* __restrict__ dst, int n4) {
  int i = blockIdx.x * 256 + threadIdx.x;
  if (i < n4) {
    float4 f = ((const float4*)src)[i];
    ushort4 o;
    o.x = f2bf(f.x); o.y = f2bf(f.y); o.z = f2bf(f.z); o.w = f2bf(f.w);
    ((ushort4*)dst)[i] = o;
  }
}

// ---------------- QKV GEMM: C[32768][2304] = A[32768][768] * Bt[2304][768]^T
// epilogue scatters q (scaled), k, and v transposed, all bf16.
__global__ __launch_bounds__(256) void qkv_gemm(
    const u16* __restrict__ A, const u16* __restrict__ Bt,
    u16* __restrict__ q, u16* __restrict__ k, u16* __restrict__ vT) {
  const int K = 768;
  __shared__ u16 As[128][72];   // +8 pad: stride 36 dwords -> 2-way banks (free)
  __shared__ u16 Bs[128][72];
  int tid = threadIdx.x;
  int wave = tid >> 6, lane = tid & 63;
  int quad = lane >> 4, lrow = lane & 15;
  int m0 = blockIdx.y * 128, n0 = blockIdx.x * 128;
  int wr = (wave >> 1) * 64, wc = (wave & 1) * 64;
  int lr = tid >> 3, lc = (tid & 7) * 8;
  const u16* Ap = A + (size_t)(m0 + lr) * K + lc;
  const u16* Bp = Bt + (size_t)(n0 + lr) * K + lc;
  f32x4 acc[4][4] = {};
  for (int k0 = 0; k0 < K; k0 += 64) {
#pragma unroll
    for (int r = 0; r < 4; r++) {
      *(uint4*)(&As[lr + 32 * r][lc]) = *(const uint4*)(Ap + (size_t)(32 * r) * K + k0);
      *(uint4*)(&Bs[lr + 32 * r][lc]) = *(const uint4*)(Bp + (size_t)(32 * r) * K + k0);
    }
    __syncthreads();
#pragma unroll
    for (int kk = 0; kk < 2; kk++) {
      bf16x8 av[4], bv[4];
#pragma unroll
      for (int i = 0; i < 4; i++) av[i] = *(const bf16x8*)(&As[wr + i * 16 + lrow][kk * 32 + quad * 8]);
#pragma unroll
      for (int j = 0; j < 4; j++) bv[j] = *(const bf16x8*)(&Bs[wc + j * 16 + lrow][kk * 32 + quad * 8]);
#pragma unroll
      for (int i = 0; i < 4; i++)
#pragma unroll
        for (int j = 0; j < 4; j++)
          acc[i][j] = mfma16(av[i], bv[j], acc[i][j]);
    }
    __syncthreads();
  }
  // epilogue: n = t*768 + h*64 + d; t,h uniform per (wave,j) since tiles are 16-aligned
#pragma unroll
  for (int j = 0; j < 4; j++) {
    int nb = n0 + wc + j * 16;
    int t = nb / 768;
    int rem = nb - t * 768;
    int h = rem >> 6;
    int d = (rem & 63) + lrow;
#pragma unroll
    for (int i = 0; i < 4; i++) {
#pragma unroll
      for (int r = 0; r < 4; r++) {
        int m = m0 + wr + i * 16 + quad * 4 + r;
        int b = m >> 7, seq = m & 127;
        size_t base = ((size_t)(b * 12 + h)) * 8192;
        float val = acc[i][j][r];
        if (t == 0)      q[base + seq * 64 + d] = f2bf(val * 0.125f);  // scale = hd^-0.5
        else if (t == 1) k[base + seq * 64 + d] = f2bf(val);
        else             vT[base + d * 128 + seq] = f2bf(val);
      }
    }
  }
}

// ---------------- attention: one block per (b,h) ----------------
__global__ __launch_bounds__(256) void attn_kernel(
    const u16* __restrict__ q, const u16* __restrict__ k, const u16* __restrict__ vT,
    const float* __restrict__ mask, const float* __restrict__ bias_table,
    u16* __restrict__ attn_out) {
  __shared__ u16 qs[128][72];
  __shared__ u16 ks[128][72];
  __shared__ u16 vTs[64][136];
  __shared__ float S[128][129];
  __shared__ u16 ps[128][136];
  __shared__ float bias_s[255];
  __shared__ float pm[128][2], pl[128][2];
  int tid = threadIdx.x;
  int wave = tid >> 6, lane = tid & 63;
  int quad = lane >> 4, lrow = lane & 15;
  int bh = blockIdx.x;
  int b = bh / 12, h = bh - b * 12;
  int w = b & 63;  // window index: b = b_outer*64 + w
  if (tid < 255) bias_s[tid] = bias_table[tid * 12 + h];
  int lr = tid >> 3, lc = (tid & 7) * 8;
  const u16* qg = q + (size_t)bh * 8192;
  const u16* kg = k + (size_t)bh * 8192;
  const u16* vg = vT + (size_t)bh * 8192;
#pragma unroll
  for (int r = 0; r < 4; r++) {
    *(uint4*)(&qs[lr + 32 * r][lc]) = *(const uint4*)(qg + (lr + 32 * r) * 64 + lc);
    *(uint4*)(&ks[lr + 32 * r][lc]) = *(const uint4*)(kg + (lr + 32 * r) * 64 + lc);
  }
  int vr = tid >> 4, vc = (tid & 15) * 8;
#pragma unroll
  for (int r = 0; r < 4; r++)
    *(uint4*)(&vTs[vr + 16 * r][vc]) = *(const uint4*)(vg + (vr + 16 * r) * 128 + vc);
  __syncthreads();

  // S = (q*scale) k^T ; each wave: rows [wave*32, wave*32+32)
  f32x4 sacc[2][8] = {};
#pragma unroll
  for (int kk = 0; kk < 2; kk++) {
    bf16x8 av[2], bv[8];
#pragma unroll
    for (int i = 0; i < 2; i++) av[i] = *(const bf16x8*)(&qs[wave * 32 + i * 16 + lrow][kk * 32 + quad * 8]);
#pragma unroll
    for (int j = 0; j < 8; j++) bv[j] = *(const bf16x8*)(&ks[j * 16 + lrow][kk * 32 + quad * 8]);
#pragma unroll
    for (int i = 0; i < 2; i++)
#pragma unroll
      for (int j = 0; j < 8; j++)
        sacc[i][j] = mfma16(av[i], bv[j], sacc[i][j]);
  }
  const float* mrow = mask + (size_t)w * 16384;
#pragma unroll
  for (int i = 0; i < 2; i++)
#pragma unroll
    for (int j = 0; j < 8; j++)
#pragma unroll
      for (int r = 0; r < 4; r++) {
        int row = wave * 32 + i * 16 + quad * 4 + r;
        int col = j * 16 + lrow;
        S[row][col] = sacc[i][j][r] + bias_s[row - col + 127] + mrow[row * 128 + col];
      }
  __syncthreads();

  // softmax: 2 threads per row (64 cols each), online max/sum, fp32
  {
    int r = tid >> 1, half = tid & 1, c0 = half * 64;
    float mx = -3.4e38f, l = 0.f;
    for (int c = c0; c < c0 + 64; c++) {
      float s = S[r][c];
      float nm = fmaxf(mx, s);
      l = l * __expf(mx - nm) + __expf(s - nm);
      mx = nm;
    }
    pm[r][half] = mx; pl[r][half] = l;
    __syncthreads();
    float ma = pm[r][0], mb = pm[r][1];
    float M = fmaxf(ma, mb);
    float L = pl[r][0] * __expf(ma - M) + pl[r][1] * __expf(mb - M);
    float inv = 1.f / L;
    for (int c = c0; c < c0 + 64; c++)
      ps[r][c] = f2bf(__expf(S[r][c] - M) * inv);
  }
  __syncthreads();

  // O = P V  (vT gives contiguous B-fragments)
  f32x4 oacc[2][4] = {};
#pragma unroll
  for (int kk = 0; kk < 4; kk++) {
    bf16x8 av[2], bv[4];
#pragma unroll
    for (int i = 0; i < 2; i++) av[i] = *(const bf16x8*)(&ps[wave * 32 + i * 16 + lrow][kk * 32 + quad * 8]);
#pragma unroll
    for (int j = 0; j < 4; j++) bv[j] = *(const bf16x8*)(&vTs[j * 16 + lrow][kk * 32 + quad * 8]);
#pragma unroll
    for (int i = 0; i < 2; i++)
#pragma unroll
      for (int j = 0; j < 4; j++)
        oacc[i][j] = mfma16(av[i], bv[j], oacc[i][j]);
  }
#pragma unroll
  for (int i = 0; i < 2; i++)
#pragma unroll
    for (int j = 0; j < 4; j++)
#pragma unroll
      for (int r = 0; r < 4; r++) {
        int seq = wave * 32 + i * 16 + quad * 4 + r;
        int d = j * 16 + lrow;
        attn_out[((size_t)(b * 128 + seq)) * 768 + h * 64 + d] = f2bf(oacc[i][j][r]);
      }
}

// ---------------- proj GEMM: out[32768][768] = A[32768][768] * Bt[768][768]^T + bias
__global__ __launch_bounds__(256) void proj_gemm(
    const u16* __restrict__ A, const u16* __restrict__ Bt,
    const float* __restrict__ bias, float* __restrict__ out) {
  const int K = 768;
  __shared__ u16 As[128][72];
  __shared__ u16 Bs[128][72];
  int tid = threadIdx.x;
  int wave = tid >> 6, lane = tid & 63;
  int quad = lane >> 4, lrow = lane & 15;
  int m0 = blockIdx.y * 128, n0 = blockIdx.x * 128;
  int wr = (wave >> 1) * 64, wc = (wave & 1) * 64;
  int lr = tid >> 3, lc = (tid & 7) * 8;
  const u16* Ap = A + (size_t)(m0 + lr) * K + lc;
  const u16* Bp = Bt + (size_t)(n0 + lr) * K + lc;
  f32x4 acc[4][4] = {};
  for (int k0 = 0; k0 < K; k0 += 64) {
#pragma unroll
    for (int r = 0; r < 4; r++) {
      *(uint4*)(&As[lr + 32 * r][lc]) = *(const uint4*)(Ap + (size_t)(32 * r) * K + k0);
      *(uint4*)(&Bs[lr + 32 * r][lc]) = *(const uint4*)(Bp + (size_t)(32 * r) * K + k0);
    }
    __syncthreads();
#pragma unroll
    for (int kk = 0; kk < 2; kk++) {
      bf16x8 av[4], bv[4];
#pragma unroll
      for (int i = 0; i < 4; i++) av[i] = *(const bf16x8*)(&As[wr + i * 16 + lrow][kk * 32 + quad * 8]);
#pragma unroll
      for (int j = 0; j < 4; j++) bv[j] = *(const bf16x8*)(&Bs[wc + j * 16 + lrow][kk * 32 + quad * 8]);
#pragma unroll
      for (int i = 0; i < 4; i++)
#pragma unroll
        for (int j = 0; j < 4; j++)
          acc[i][j] = mfma16(av[i], bv[j], acc[i][j]);
    }
    __syncthreads();
  }
#pragma unroll
  for (int i = 0; i < 4; i++)
#pragma unroll
    for (int j = 0; j < 4; j++)
#pragma unroll
      for (int r = 0; r < 4; r++) {
        int m = m0 + wr + i * 16 + quad * 4 + r;
        int n = n0 + wc + j * 16 + lrow;
        out[(size_t)m * 768 + n] = acc[i][j][r] + bias[n];
      }
}

extern "C" void kernel_launch(void* const* d_in, const int* in_sizes, int n_in,
                              void* d_out, int out_size, void* d_ws, size_t ws_size,
                              hipStream_t stream) {
  const float* x          = (const float*)d_in[0];
  const float* mask       = (const float*)d_in[1];
  const float* qkv_w      = (const float*)d_in[2];
  const float* bias_table = (const float*)d_in[3];
  const float* proj_w     = (const float*)d_in[4];
  const float* proj_b     = (const float*)d_in[5];
  float* out = (float*)d_out;
  char* ws = (char*)d_ws;
  // workspace layout (bytes)
  u16* q_b    = (u16*)(ws);                    // 50331648
  u16* k_b    = (u16*)(ws + 50331648);         // 50331648
  u16* vT_b   = (u16*)(ws + 100663296);        // 50331648
  u16* x_b    = (u16*)(ws + 150994944);        // 50331648 (x bf16, then reused as attn_out)
  u16* qw_b   = (u16*)(ws + 201326592);        // 3538944
  u16* pw_b   = (u16*)(ws + 204865536);        // 1179648  -> total 206045184 B
  u16* attn_b = x_b;

  cvt_bf16<<<24576, 256, 0, stream>>>(x, x_b, 6291456);
  cvt_bf16<<<1728, 256, 0, stream>>>(qkv_w, qw_b, 442368);
  cvt_bf16<<<576, 256, 0, stream>>>(proj_w, pw_b, 147456);
  qkv_gemm<<<dim3(18, 256), 256, 0, stream>>>(x_b, qw_b, q_b, k_b, vT_b);
  attn_kernel<<<3072, 256, 0, stream>>>(q_b, k_b, vT_b, mask, bias_table, attn_b);
  proj_gemm<<<dim3(6, 256), 256, 0, stream>>>(attn_b, pw_b, proj_b, out);
}

// Round 2
// 506.793 us; speedup vs baseline: 1.1061x; 1.1061x over previous
//
#include <hip/hip_runtime.h>
#include <hip/hip_bf16.h>
#include <stdint.h>

typedef unsigned short u16;
typedef __bf16 bf16x8 __attribute__((ext_vector_type(8)));
typedef float f32x4 __attribute__((ext_vector_type(4)));

__device__ __forceinline__ u16 f2bf(float f) {
  union { float f; uint32_t u; } v; v.f = f;
  uint32_t u = v.u;
  return (u16)((u + 0x7FFFu + ((u >> 16) & 1u)) >> 16);
}

__device__ __forceinline__ f32x4 mfma16(bf16x8 a, bf16x8 b, f32x4 c) {
  return __builtin_amdgcn_mfma_f32_16x16x32_bf16(a, b, c, 0, 0, 0);
}

#define GLOBAL_TO_LDS16(g, l)                                                  \
  __builtin_amdgcn_global_load_lds(                                            \
      (const __attribute__((address_space(1))) void*)(g),                      \
      (__attribute__((address_space(3))) void*)(l), 16, 0, 0)

// ---------------- f32 -> bf16 conversion, 4 elts/thread ----------------
__global__ void cvt_bf16(const float* __restrict__ src, u16* __restrict__ dst, int n4) {
  int i = blockIdx.x * 256 + threadIdx.x;
  if (i < n4) {
    float4 f = ((const float4*)src)[i];
    ushort4 o;
    o.x = f2bf(f.x); o.y = f2bf(f.y); o.z = f2bf(f.z); o.w = f2bf(f.w);
    ((ushort4*)dst)[i] = o;
  }
}

// ---------------- QKV GEMM: C[32768][2304] = A[32768][768] * Bt[2304][768]^T
// global_load_lds(16B) staging into unpadded [128][64] tiles with XOR chunk
// swizzle: chunk stored at (c ^ (row&7)) -> frag ds_read_b128 is 2-way (free).
__global__ __launch_bounds__(256) void qkv_gemm(
    const u16* __restrict__ A, const u16* __restrict__ Bt,
    u16* __restrict__ q, u16* __restrict__ k, u16* __restrict__ vT) {
  const int K = 768;
  __shared__ u16 As[128 * 64];
  __shared__ u16 Bs[128 * 64];
  int tid = threadIdx.x;
  int wave = tid >> 6, lane = tid & 63;
  int quad = lane >> 4, lrow = lane & 15;
  int m0 = blockIdx.y * 128, n0 = blockIdx.x * 128;
  int wr = (wave >> 1) * 64, wc = (wave & 1) * 64;

  const u16* asrc[4]; const u16* bsrc[4]; int ldst[4];
#pragma unroll
  for (int s = 0; s < 4; s++) {
    int p = (wave * 4 + s) * 64 + lane;     // chunk position in LDS tile
    int row = p >> 3, cp = p & 7;
    int c = cp ^ (row & 7);                  // global chunk this lane fetches
    asrc[s] = A + (size_t)(m0 + row) * K + c * 8;
    bsrc[s] = Bt + (size_t)(n0 + row) * K + c * 8;
    ldst[s] = p * 8;
  }
  f32x4 acc[4][4] = {};
  for (int k0 = 0; k0 < K; k0 += 64) {
#pragma unroll
    for (int s = 0; s < 4; s++) {
      GLOBAL_TO_LDS16(asrc[s] + k0, As + ldst[s]);
      GLOBAL_TO_LDS16(bsrc[s] + k0, Bs + ldst[s]);
    }
    __syncthreads();
#pragma unroll
    for (int kk = 0; kk < 2; kk++) {
      bf16x8 av[4], bv[4];
#pragma unroll
      for (int i = 0; i < 4; i++) {
        int r = wr + i * 16 + lrow;
        av[i] = *(const bf16x8*)(As + r * 64 + ((((kk << 2) | quad) ^ (r & 7)) << 3));
      }
#pragma unroll
      for (int j = 0; j < 4; j++) {
        int r = wc + j * 16 + lrow;
        bv[j] = *(const bf16x8*)(Bs + r * 64 + ((((kk << 2) | quad) ^ (r & 7)) << 3));
      }
#pragma unroll
      for (int i = 0; i < 4; i++)
#pragma unroll
        for (int j = 0; j < 4; j++)
          acc[i][j] = mfma16(av[i], bv[j], acc[i][j]);
    }
    __syncthreads();
  }
#pragma unroll
  for (int j = 0; j < 4; j++) {
    int nb = n0 + wc + j * 16;
    int t = nb / 768;
    int rem = nb - t * 768;
    int h = rem >> 6;
    int d = (rem & 63) + lrow;
#pragma unroll
    for (int i = 0; i < 4; i++) {
#pragma unroll
      for (int r = 0; r < 4; r++) {
        int m = m0 + wr + i * 16 + quad * 4 + r;
        int b = m >> 7, seq = m & 127;
        size_t base = ((size_t)(b * 12 + h)) * 8192;
        float val = acc[i][j][r];
        if (t == 0)      q[base + seq * 64 + d] = f2bf(val * 0.125f);  // hd^-0.5
        else if (t == 1) k[base + seq * 64 + d] = f2bf(val);
        else             vT[base + d * 128 + seq] = f2bf(val);
      }
    }
  }
}

// ---------------- attention: one block per (b,h); in-register softmax ----
__global__ __launch_bounds__(256) void attn_kernel(
    const u16* __restrict__ q, const u16* __restrict__ k, const u16* __restrict__ vT,
    const float* __restrict__ mask, const float* __restrict__ bias_table,
    u16* __restrict__ attn_out) {
  __shared__ u16 qk_s[2 * 128 * 72];   // qs | ks ; aliased by ps (128x136) later
  __shared__ u16 vTs[64][136];
  __shared__ float bias_s[255];
  u16* qs = qk_s;
  u16* ks = qk_s + 128 * 72;
  u16* ps = qk_s;                      // P, stride 136 (34816 B <= 36864 B)
  int tid = threadIdx.x;
  int wave = tid >> 6, lane = tid & 63;
  int quad = lane >> 4, lrow = lane & 15;
  int bh = blockIdx.x;
  int b = bh / 12, h = bh - b * 12;
  int w = b & 63;
  if (tid < 255) bias_s[tid] = bias_table[tid * 12 + h];
  int lr = tid >> 3, lc = (tid & 7) * 8;
  const u16* qg = q + (size_t)bh * 8192;
  const u16* kg = k + (size_t)bh * 8192;
  const u16* vg = vT + (size_t)bh * 8192;
#pragma unroll
  for (int r = 0; r < 4; r++) {
    *(uint4*)(qs + (lr + 32 * r) * 72 + lc) = *(const uint4*)(qg + (lr + 32 * r) * 64 + lc);
    *(uint4*)(ks + (lr + 32 * r) * 72 + lc) = *(const uint4*)(kg + (lr + 32 * r) * 64 + lc);
  }
  int vr = tid >> 4, vc = (tid & 15) * 8;
#pragma unroll
  for (int r = 0; r < 4; r++)
    *(uint4*)(&vTs[vr + 16 * r][vc]) = *(const uint4*)(vg + (vr + 16 * r) * 128 + vc);
  __syncthreads();

  // S = q k^T ; wave handles rows [wave*32, wave*32+32)
  f32x4 sacc[2][8] = {};
#pragma unroll
  for (int kk = 0; kk < 2; kk++) {
    bf16x8 av[2], bv[8];
#pragma unroll
    for (int i = 0; i < 2; i++)
      av[i] = *(const bf16x8*)(qs + (wave * 32 + i * 16 + lrow) * 72 + kk * 32 + quad * 8);
#pragma unroll
    for (int j = 0; j < 8; j++)
      bv[j] = *(const bf16x8*)(ks + (j * 16 + lrow) * 72 + kk * 32 + quad * 8);
#pragma unroll
    for (int i = 0; i < 2; i++)
#pragma unroll
      for (int j = 0; j < 8; j++)
        sacc[i][j] = mfma16(av[i], bv[j], sacc[i][j]);
  }
  // bias + mask, then in-register softmax over MFMA C-layout:
  // row = wave*32 + i*16 + quad*4 + r lives across lrow lanes and j regs.
  const float* mrow = mask + (size_t)w * 16384;
#pragma unroll
  for (int i = 0; i < 2; i++)
#pragma unroll
    for (int j = 0; j < 8; j++)
#pragma unroll
      for (int r = 0; r < 4; r++) {
        int row = wave * 32 + i * 16 + quad * 4 + r;
        int col = j * 16 + lrow;
        sacc[i][j][r] += bias_s[row - col + 127] + mrow[row * 128 + col];
      }
#pragma unroll
  for (int i = 0; i < 2; i++)
#pragma unroll
    for (int r = 0; r < 4; r++) {
      float m = sacc[i][0][r];
#pragma unroll
      for (int j = 1; j < 8; j++) m = fmaxf(m, sacc[i][j][r]);
#pragma unroll
      for (int d = 1; d < 16; d <<= 1) m = fmaxf(m, __shfl_xor(m, d, 64));
      float sum = 0.f;
#pragma unroll
      for (int j = 0; j < 8; j++) {
        float e = __expf(sacc[i][j][r] - m);
        sacc[i][j][r] = e;
        sum += e;
      }
#pragma unroll
      for (int d = 1; d < 16; d <<= 1) sum += __shfl_xor(sum, d, 64);
      float inv = 1.f / sum;
#pragma unroll
      for (int j = 0; j < 8; j++) sacc[i][j][r] *= inv;
    }
  __syncthreads();   // all waves done reading qs/ks -> safe to alias with ps
#pragma unroll
  for (int i = 0; i < 2; i++)
#pragma unroll
    for (int j = 0; j < 8; j++)
#pragma unroll
      for (int r = 0; r < 4; r++)
        ps[(wave * 32 + i * 16 + quad * 4 + r) * 136 + j * 16 + lrow] = f2bf(sacc[i][j][r]);
  __syncthreads();

  // O = P V
  f32x4 oacc[2][4] = {};
#pragma unroll
  for (int kk = 0; kk < 4; kk++) {
    bf16x8 av[2], bv[4];
#pragma unroll
    for (int i = 0; i < 2; i++)
      av[i] = *(const bf16x8*)(ps + (wave * 32 + i * 16 + lrow) * 136 + kk * 32 + quad * 8);
#pragma unroll
    for (int j = 0; j < 4; j++)
      bv[j] = *(const bf16x8*)(&vTs[j * 16 + lrow][kk * 32 + quad * 8]);
#pragma unroll
    for (int i = 0; i < 2; i++)
#pragma unroll
      for (int j = 0; j < 4; j++)
        oacc[i][j] = mfma16(av[i], bv[j], oacc[i][j]);
  }
#pragma unroll
  for (int i = 0; i < 2; i++)
#pragma unroll
    for (int j = 0; j < 4; j++)
#pragma unroll
      for (int r = 0; r < 4; r++) {
        int seq = wave * 32 + i * 16 + quad * 4 + r;
        int d = j * 16 + lrow;
        attn_out[((size_t)(b * 128 + seq)) * 768 + h * 64 + d] = f2bf(oacc[i][j][r]);
      }
}

// ---------------- proj GEMM: out[32768][768] = A[32768][768] * Bt[768][768]^T + bias
__global__ __launch_bounds__(256) void proj_gemm(
    const u16* __restrict__ A, const u16* __restrict__ Bt,
    const float* __restrict__ bias, float* __restrict__ out) {
  const int K = 768;
  __shared__ u16 As[128 * 64];
  __shared__ u16 Bs[128 * 64];
  int tid = threadIdx.x;
  int wave = tid >> 6, lane = tid & 63;
  int quad = lane >> 4, lrow = lane & 15;
  int m0 = blockIdx.y * 128, n0 = blockIdx.x * 128;
  int wr = (wave >> 1) * 64, wc = (wave & 1) * 64;

  const u16* asrc[4]; const u16* bsrc[4]; int ldst[4];
#pragma unroll
  for (int s = 0; s < 4; s++) {
    int p = (wave * 4 + s) * 64 + lane;
    int row = p >> 3, cp = p & 7;
    int c = cp ^ (row & 7);
    asrc[s] = A + (size_t)(m0 + row) * K + c * 8;
    bsrc[s] = Bt + (size_t)(n0 + row) * K + c * 8;
    ldst[s] = p * 8;
  }
  f32x4 acc[4][4] = {};
  for (int k0 = 0; k0 < K; k0 += 64) {
#pragma unroll
    for (int s = 0; s < 4; s++) {
      GLOBAL_TO_LDS16(asrc[s] + k0, As + ldst[s]);
      GLOBAL_TO_LDS16(bsrc[s] + k0, Bs + ldst[s]);
    }
    __syncthreads();
#pragma unroll
    for (int kk = 0; kk < 2; kk++) {
      bf16x8 av[4], bv[4];
#pragma unroll
      for (int i = 0; i < 4; i++) {
        int r = wr + i * 16 + lrow;
        av[i] = *(const bf16x8*)(As + r * 64 + ((((kk << 2) | quad) ^ (r & 7)) << 3));
      }
#pragma unroll
      for (int j = 0; j < 4; j++) {
        int r = wc + j * 16 + lrow;
        bv[j] = *(const bf16x8*)(Bs + r * 64 + ((((kk << 2) | quad) ^ (r & 7)) << 3));
      }
#pragma unroll
      for (int i = 0; i < 4; i++)
#pragma unroll
        for (int j = 0; j < 4; j++)
          acc[i][j] = mfma16(av[i], bv[j], acc[i][j]);
    }
    __syncthreads();
  }
#pragma unroll
  for (int i = 0; i < 4; i++)
#pragma unroll
    for (int j = 0; j < 4; j++)
#pragma unroll
      for (int r = 0; r < 4; r++) {
        int m = m0 + wr + i * 16 + quad * 4 + r;
        int n = n0 + wc + j * 16 + lrow;
        out[(size_t)m * 768 + n] = acc[i][j][r] + bias[n];
      }
}

extern "C" void kernel_launch(void* const* d_in, const int* in_sizes, int n_in,
                              void* d_out, int out_size, void* d_ws, size_t ws_size,
                              hipStream_t stream) {
  const float* x          = (const float*)d_in[0];
  const float* mask       = (const float*)d_in[1];
  const float* qkv_w      = (const float*)d_in[2];
  const float* bias_table = (const float*)d_in[3];
  const float* proj_w     = (const float*)d_in[4];
  const float* proj_b     = (const float*)d_in[5];
  float* out = (float*)d_out;
  char* ws = (char*)d_ws;
  u16* q_b    = (u16*)(ws);                    // 50331648
  u16* k_b    = (u16*)(ws + 50331648);         // 50331648
  u16* vT_b   = (u16*)(ws + 100663296);        // 50331648
  u16* x_b    = (u16*)(ws + 150994944);        // 50331648 (x bf16, reused as attn_out)
  u16* qw_b   = (u16*)(ws + 201326592);        // 3538944
  u16* pw_b   = (u16*)(ws + 204865536);        // 1179648
  u16* attn_b = x_b;

  cvt_bf16<<<24576, 256, 0, stream>>>(x, x_b, 6291456);
  cvt_bf16<<<1728, 256, 0, stream>>>(qkv_w, qw_b, 442368);
  cvt_bf16<<<576, 256, 0, stream>>>(proj_w, pw_b, 147456);
  qkv_gemm<<<dim3(18, 256), 256, 0, stream>>>(x_b, qw_b, q_b, k_b, vT_b);
  attn_kernel<<<3072, 256, 0, stream>>>(q_b, k_b, vT_b, mask, bias_table, attn_b);
  proj_gemm<<<dim3(6, 256), 256, 0, stream>>>(attn_b, pw_b, proj_b, out);
}